// Round 11
// baseline (275.026 us; speedup 1.0000x reference)
//
#include <hip/hip_runtime.h>
#include <hip/hip_fp16.h>
#include <cstdint>

#define BATCH 512
#define CIN   64
#define HH    32
#define WW    64
#define HW    2048
#define C1    32
#define C2    16
#define C3    8
#define C4    4
#define NOUT  256
#define KFC   8192
#define NODES 128
#define KS    16                      // FC K-split
#define GF_SIZE (BATCH * NODES * CIN)

typedef __attribute__((ext_vector_type(8))) short bfrag;   // 8 bf16 (4 VGPRs)
typedef __attribute__((ext_vector_type(4))) float ffrag;   // 4 fp32 acc

__device__ __forceinline__ ushort bf_trunc(float f) { return (ushort)(__float_as_uint(f) >> 16); }
__device__ __forceinline__ float  bf_truncf(float f) { return __uint_as_float(__float_as_uint(f) & 0xffff0000u); }
__device__ __forceinline__ ushort f2bf(float f) {
  uint32_t u = __float_as_uint(f);
  return (ushort)((u + 0x7fffu + ((u >> 16) & 1u)) >> 16);
}
__device__ __forceinline__ uint32_t pack2(float a, float b) {
  return (uint32_t)f2bf(a) | ((uint32_t)f2bf(b) << 16);
}
__device__ __forceinline__ uint32_t packhi2(float a, float b) {
  return (uint32_t)bf_trunc(a) | ((uint32_t)bf_trunc(b) << 16);
}
__device__ __forceinline__ ushort f2h(float f) { return __half_as_ushort(__float2half_rn(f)); }
__device__ __forceinline__ uint32_t packh2(float a, float b) {
  return (uint32_t)f2h(a) | ((uint32_t)f2h(b) << 16);
}
__device__ __forceinline__ float h2f(uint32_t u) { return __half2float(__ushort_as_half((ushort)u)); }
__device__ __forceinline__ float bf2f(ushort u) { return __uint_as_float(((uint32_t)u) << 16); }

// ---------------------------------------------------------------------------
// K0: x NCHW fp32 -> xt NHWC bf16 (RTN), LDS-staged for coalesced stores.
// (R9 proven: reads coalesced along px; stores 4 KB contiguous per wave.)
// ---------------------------------------------------------------------------
__global__ __launch_bounds__(256) void k_xpose(
    const float* __restrict__ x, ushort* __restrict__ xt)
{
  __shared__ uint32_t tb[256 * 33];
  const int t  = threadIdx.x;
  const int b  = blockIdx.y;
  const int rg = blockIdx.x;                 // 4-row group, 256 px
  const float* xp = x + (size_t)b * CIN * HW + rg * 256 + t;
  #pragma unroll
  for (int j = 0; j < 32; ++j) {
    float v0 = xp[(size_t)(2 * j) * HW];
    float v1 = xp[(size_t)(2 * j + 1) * HW];
    tb[t * 33 + j] = pack2(v0, v1);
  }
  __syncthreads();
  ushort* op = xt + ((size_t)b * HW + rg * 256) * CIN;
  #pragma unroll
  for (int k = 0; k < 8; ++k) {
    const int u = k * 256 + t;
    const int p = u >> 3, q = u & 7;
    uint4 v;
    v.x = tb[p * 33 + q * 4 + 0];
    v.y = tb[p * 33 + q * 4 + 1];
    v.z = tb[p * 33 + q * 4 + 2];
    v.w = tb[p * 33 + q * 4 + 3];
    *(uint4*)(op + (size_t)u * 8) = v;
  }
}

// ---------------------------------------------------------------------------
// K1: conv1+conv2+conv3+conv4 fused, WHOLE IMAGE per block (round 11).
// 1024 threads (16 waves = 4 waves/SIMD), grid = cb blocks. Zero halo
// re-read/compute: h1 stores 32 valid rows + 1 shared ZERO row (idx 32);
// out-of-range row reads clamp to the zero row (== padding semantics).
//  Stage 1 LDS: h1 [33][66][64B] = 139392 B.
//  Stage 2 LDS (reuse): h2 [32][64][16 fp16] (65536) + h3 [33][64][9] f32
//           (76032 B, row 32 = zero) = 141568 B total.
// x never re-read across row tiles; conv1 MFMA -33%, conv2 -19% vs R10.
// ---------------------------------------------------------------------------
__global__ __launch_bounds__(1024) void k_conv1234(
    const ushort* __restrict__ xt, const float* __restrict__ w11, const float* __restrict__ b11,
    const float* __restrict__ w12, const float* __restrict__ b12,
    const float* __restrict__ w21, const float* __restrict__ b21,
    const float* __restrict__ w22, const float* __restrict__ b22,
    ushort* __restrict__ h4h, ushort* __restrict__ h4l, int b0)
{
  __shared__ __align__(16) char smem[141568];
  const int tid = threadIdx.x;
  const int l   = tid & 63;
  const int wv  = tid >> 6;    // 0..15
  const int lr  = l & 15;
  const int lg  = l >> 4;
  const int bg  = b0 + blockIdx.x;
  const ushort* xtb = xt + (size_t)bg * HW * CIN;

  // init: pad cols (0,65) of rows 0..32, and full zero row 32. 16 B/thread.
  if (tid < 264) {            // pad cols: 33 rows x 2 cols x 64 B = 264 x 16 B
    int row = tid >> 3, rem = tid & 7;
    int colb = (rem < 4) ? 0 : 65, q = rem & 3;
    *(uint4*)(smem + ((row * 66 + colb) << 6) + q * 16) = uint4{0u, 0u, 0u, 0u};
  } else if (tid < 528) {     // zero row 32: 66 cols x 64 B = 264 x 16 B
    int idx = tid - 264;
    int col = idx >> 2, q = idx & 3;
    *(uint4*)(smem + ((32 * 66 + col) << 6) + q * 16) = uint4{0u, 0u, 0u, 0u};
  }

  // W1 fragments from global (hi/lo split keeps W fp32-grade)
  bfrag w1h[2][2], w1l[2][2];
  #pragma unroll
  for (int m = 0; m < 2; ++m) {
    #pragma unroll
    for (int ks = 0; ks < 2; ++ks) {
      const float* wp = w11 + (m * 16 + lr) * 64 + ks * 32 + lg * 8;
      #pragma unroll
      for (int e = 0; e < 8; ++e) {
        float v = wp[e];
        w1h[m][ks][e] = (short)bf_trunc(v);
        w1l[m][ks][e] = (short)f2bf(v - bf_truncf(v));
      }
    }
  }
  float bias1[2][4];
  #pragma unroll
  for (int m = 0; m < 2; ++m) {
    #pragma unroll
    for (int r = 0; r < 4; ++r) bias1[m][r] = b11[m * 16 + lg * 4 + r];
  }

  // ---- Phase A: conv1 -> h1 LDS. 128 tiles (32 rows x 4 col-tiles), 8/wave,
  // 2-deep fragment prefetch; coalesced dwordx4 loads from xt. All rows valid.
  auto ldfrag = [&](int nt, bfrag& f0, bfrag& f1) {
    const int ry = nt >> 2, col0 = (nt & 3) << 4;
    const ushort* xp = xtb + (size_t)(ry * WW + col0 + lr) * CIN + lg * 8;
    f0 = *(const bfrag*)xp;
    f1 = *(const bfrag*)(xp + 32);
  };
  auto comp = [&](int nt, bfrag f0, bfrag f1) {
    const int ry = nt >> 2, col0 = (nt & 3) << 4;
    const int colb = col0 + 1 + lr;
    ffrag a0 = {0.f, 0.f, 0.f, 0.f}, a1 = {0.f, 0.f, 0.f, 0.f};
    a0 = __builtin_amdgcn_mfma_f32_16x16x32_bf16(w1h[0][0], f0, a0, 0, 0, 0);
    a0 = __builtin_amdgcn_mfma_f32_16x16x32_bf16(w1l[0][0], f0, a0, 0, 0, 0);
    a0 = __builtin_amdgcn_mfma_f32_16x16x32_bf16(w1h[0][1], f1, a0, 0, 0, 0);
    a0 = __builtin_amdgcn_mfma_f32_16x16x32_bf16(w1l[0][1], f1, a0, 0, 0, 0);
    a1 = __builtin_amdgcn_mfma_f32_16x16x32_bf16(w1h[1][0], f0, a1, 0, 0, 0);
    a1 = __builtin_amdgcn_mfma_f32_16x16x32_bf16(w1l[1][0], f0, a1, 0, 0, 0);
    a1 = __builtin_amdgcn_mfma_f32_16x16x32_bf16(w1h[1][1], f1, a1, 0, 0, 0);
    a1 = __builtin_amdgcn_mfma_f32_16x16x32_bf16(w1l[1][1], f1, a1, 0, 0, 0);
    #pragma unroll
    for (int m = 0; m < 2; ++m) {
      float v0 = fmaxf((m ? a1[0] : a0[0]) + bias1[m][0], 0.f);
      float v1 = fmaxf((m ? a1[1] : a0[1]) + bias1[m][1], 0.f);
      float v2 = fmaxf((m ? a1[2] : a0[2]) + bias1[m][2], 0.f);
      float v3 = fmaxf((m ? a1[3] : a0[3]) + bias1[m][3], 0.f);
      int chunk = (m * 2 + (lg >> 1)) ^ ((colb >> 1) & 3);
      char* dst = smem + ((ry * 66 + colb) << 6) + (chunk << 4) + (lg & 1) * 8;
      *(uint2*)dst = uint2{pack2(v0, v1), pack2(v2, v3)};
    }
  };

  {
    bfrag c0, c1, n0, n1;
    ldfrag(wv * 8 + 0, c0, c1);
    #pragma unroll
    for (int i = 0; i < 8; ++i) {
      if (i < 7) ldfrag(wv * 8 + i + 1, n0, n1);
      comp(wv * 8 + i, c0, c1);
      c0 = n0; c1 = n1;
    }
  }
  __syncthreads();

  // W2 fragments from global (after barrier; keeps Phase-A VGPR low).
  bfrag w2h[9], w2l[9];
  #pragma unroll
  for (int t = 0; t < 9; ++t) {
    const float* wp = w12 + lr * 288 + t;
    #pragma unroll
    for (int e = 0; e < 8; ++e) {
      float v = wp[(lg * 8 + e) * 9];
      w2h[t][e] = (short)bf_trunc(v);
      w2l[t][e] = (short)f2bf(v - bf_truncf(v));
    }
  }
  float bias2[4];
  #pragma unroll
  for (int r = 0; r < 4; ++r) bias2[r] = b12[lg * 4 + r];

  // ---- Phase B: conv2 -> h2 fp16 in regs. 128 tiles (32 rows x 4), 8/wave.
  // h1 row map: out-of-range -> zero row 32.
  uint32_t ph0[8], ph1[8];
  #pragma unroll
  for (int i = 0; i < 8; ++i) {
    const int nt   = wv * 8 + i;
    const int hy   = nt >> 2;             // 0..31
    const int col0 = (nt & 3) << 4;
    ffrag acc = {0.f, 0.f, 0.f, 0.f};
    #pragma unroll
    for (int ky = 0; ky < 3; ++ky) {
      const int yv  = hy - 1 + ky;
      const int row = ((unsigned)yv < 32u) ? yv : 32;
      #pragma unroll
      for (int kx = 0; kx < 3; ++kx) {
        const int colb  = col0 + lr + kx;
        const int chunk = lg ^ ((colb >> 1) & 3);
        const bfrag hv = *(const bfrag*)(smem + ((row * 66 + colb) << 6) + (chunk << 4));
        acc = __builtin_amdgcn_mfma_f32_16x16x32_bf16(w2h[ky * 3 + kx], hv, acc, 0, 0, 0);
        acc = __builtin_amdgcn_mfma_f32_16x16x32_bf16(w2l[ky * 3 + kx], hv, acc, 0, 0, 0);
      }
    }
    ph0[i] = packh2(fmaxf(acc[0] + bias2[0], 0.f), fmaxf(acc[1] + bias2[1], 0.f));
    ph1[i] = packh2(fmaxf(acc[2] + bias2[2], 0.f), fmaxf(acc[3] + bias2[3], 0.f));
  }
  __syncthreads();   // all h1 reads done; safe to overwrite smem

  // h2 regs -> LDS: [32 rows][64 px][16 ch fp16] = 65536 B at smem base.
  #pragma unroll
  for (int i = 0; i < 8; ++i) {
    const int nt  = wv * 8 + i;
    const int hy  = nt >> 2;
    const int col = ((nt & 3) << 4) + lr;
    *(uint2*)(smem + ((hy * 64 + col) << 5) + lg * 8) = uint2{ph0[i], ph1[i]};
  }
  __syncthreads();

  // ---- Phase C1: conv3 (1x1, 16->8) -> h3 f32 LDS [33][64][9] @ +65536
  // (row 32 = zero row for conv4's vertical padding).
  float* h3b = (float*)(smem + 65536);
  if (tid < 576) {           // zero row 32: 64 px x 9 floats
    const int px = tid / 9, c = tid - px * 9;
    h3b[(32 * 64 + px) * 9 + c] = 0.f;
  }
  #pragma unroll
  for (int it = 0; it < 2; ++it) {
    const int p  = it * 1024 + tid;
    const int ry = p >> 6, wc = p & 63;
    const uint4 ua = *(const uint4*)(smem + ((ry * 64 + wc) << 5));
    const uint4 ub = *(const uint4*)(smem + ((ry * 64 + wc) << 5) + 16);
    uint32_t uw[8] = {ua.x, ua.y, ua.z, ua.w, ub.x, ub.y, ub.z, ub.w};
    float xv[16];
    #pragma unroll
    for (int j = 0; j < 8; ++j) {
      xv[2*j]   = h2f(uw[j] & 0xffffu);
      xv[2*j+1] = h2f(uw[j] >> 16);
    }
    float acc[C3];
    #pragma unroll
    for (int o = 0; o < C3; ++o) acc[o] = b21[o];
    #pragma unroll
    for (int c = 0; c < 16; ++c) {
      float v = xv[c];
      #pragma unroll
      for (int o = 0; o < C3; ++o)
        acc[o] = fmaf(v, w21[o * 16 + c], acc[o]);   // uniform -> s_load
    }
    float* hd = h3b + (ry * 64 + wc) * 9;
    #pragma unroll
    for (int c = 0; c < C3; ++c) hd[c] = fmaxf(acc[c], 0.f);
  }
  __syncthreads();

  // ---- Phase C2: conv4 (3x3, 8->4) -> h4 bf16 hi/lo global.
  #pragma unroll
  for (int it = 0; it < 2; ++it) {
    const int p  = it * 1024 + tid;
    const int yl = p >> 6, wc = p & 63;
    float acc[C4] = {b22[0], b22[1], b22[2], b22[3]};
    #pragma unroll
    for (int ky = 0; ky < 3; ++ky) {
      const int yv  = yl - 1 + ky;
      const int row = ((unsigned)yv < 32u) ? yv : 32;
      #pragma unroll
      for (int kx = 0; kx < 3; ++kx) {
        const int wcc = wc + kx - 1;
        if (wcc < 0 || wcc >= WW) continue;
        const float* hb = h3b + (row * 64 + wcc) * 9;
        const int tap = ky * 3 + kx;
        #pragma unroll
        for (int c = 0; c < C3; ++c) {
          float v = hb[c];
          #pragma unroll
          for (int o = 0; o < C4; ++o)
            acc[o] = fmaf(v, w22[(o * 8 + c) * 9 + tap], acc[o]);  // s_load
        }
      }
    }
    const size_t base = (size_t)blockIdx.x * KFC + yl * WW + wc;
    #pragma unroll
    for (int o = 0; o < C4; ++o) {
      float v = fmaxf(acc[o], 0.f);
      h4h[base + (size_t)o * HW] = bf_trunc(v);
      h4l[base + (size_t)o * HW] = f2bf(v - bf_truncf(v));
    }
  }
}

// ---------------------------------------------------------------------------
// K2b: fcw fp32 -> bf16 hi/lo planes (once per launch, deterministic)
// ---------------------------------------------------------------------------
__global__ __launch_bounds__(256) void k_cvt_fcw(
    const float* __restrict__ w, ushort* __restrict__ hi, ushort* __restrict__ lo)
{
  const int i = (blockIdx.x * 256 + threadIdx.x) * 8;
  const float4 a = *(const float4*)(w + i);
  const float4 b = *(const float4*)(w + i + 4);
  uint4 hv, lv;
  hv.x = packhi2(a.x, a.y); hv.y = packhi2(a.z, a.w);
  hv.z = packhi2(b.x, b.y); hv.w = packhi2(b.z, b.w);
  lv.x = pack2(a.x - bf_truncf(a.x), a.y - bf_truncf(a.y));
  lv.y = pack2(a.z - bf_truncf(a.z), a.w - bf_truncf(a.w));
  lv.z = pack2(b.x - bf_truncf(b.x), b.y - bf_truncf(b.y));
  lv.w = pack2(b.z - bf_truncf(b.z), b.w - bf_truncf(b.w));
  *(uint4*)(hi + i) = hv;
  *(uint4*)(lo + i) = lv;
}

// ---------------------------------------------------------------------------
// K3: FC GEMM, MFMA bf16 3-product (hi/lo), K split KS-way, deterministic.
// ---------------------------------------------------------------------------
__global__ __launch_bounds__(256) void k_fc(
    const ushort* __restrict__ Ahp, const ushort* __restrict__ Alp,
    const ushort* __restrict__ Bhp, const ushort* __restrict__ Blp,
    float* __restrict__ zpart, int cb)
{
  const int tid = threadIdx.x;
  const int l   = tid & 63;
  const int wv  = tid >> 6;
  const int lr  = l & 15;
  const int lg  = l >> 4;
  const int m0  = blockIdx.x * 64 + (wv >> 1) * 32;
  const int n0  = blockIdx.y * 64 + (wv & 1) * 32;
  const int k0  = blockIdx.z * (KFC / KS);     // 512 per split

  int mrow[2], nrow[2];
  #pragma unroll
  for (int t = 0; t < 2; ++t) {
    int m = m0 + t * 16 + lr;
    mrow[t] = m < cb ? m : cb - 1;             // clamp; masked at write
    nrow[t] = n0 + t * 16 + lr;
  }
  ffrag acc[2][2] = {};

  #pragma unroll 1
  for (int kc = 0; kc < (KFC / KS) / 32; ++kc) {
    const int k = k0 + kc * 32 + lg * 8;
    bfrag ah[2], al[2], bh[2], bl[2];
    #pragma unroll
    for (int t = 0; t < 2; ++t) {
      ah[t] = *(const bfrag*)(Ahp + (size_t)mrow[t] * KFC + k);
      al[t] = *(const bfrag*)(Alp + (size_t)mrow[t] * KFC + k);
      bh[t] = *(const bfrag*)(Bhp + (size_t)nrow[t] * KFC + k);
      bl[t] = *(const bfrag*)(Blp + (size_t)nrow[t] * KFC + k);
    }
    #pragma unroll
    for (int mt = 0; mt < 2; ++mt) {
      #pragma unroll
      for (int nt = 0; nt < 2; ++nt) {
        acc[mt][nt] = __builtin_amdgcn_mfma_f32_16x16x32_bf16(ah[mt], bh[nt], acc[mt][nt], 0, 0, 0);
        acc[mt][nt] = __builtin_amdgcn_mfma_f32_16x16x32_bf16(ah[mt], bl[nt], acc[mt][nt], 0, 0, 0);
        acc[mt][nt] = __builtin_amdgcn_mfma_f32_16x16x32_bf16(al[mt], bh[nt], acc[mt][nt], 0, 0, 0);
      }
    }
  }

  #pragma unroll
  for (int mt = 0; mt < 2; ++mt) {
    #pragma unroll
    for (int r = 0; r < 4; ++r) {
      const int m = m0 + mt * 16 + lg * 4 + r;
      if (m < cb) {
        #pragma unroll
        for (int nt = 0; nt < 2; ++nt)
          zpart[((size_t)blockIdx.z * cb + m) * NOUT + n0 + nt * 16 + lr] = acc[mt][nt][r];
      }
    }
  }
}

// ---------------------------------------------------------------------------
// K5: fused coord + bilinear gather reading xt (NHWC bf16), XCD-grouped.
// ---------------------------------------------------------------------------
__global__ __launch_bounds__(256) void k_gather(
    const ushort* __restrict__ xt, const float* __restrict__ zpart,
    const float* __restrict__ fcb, float* __restrict__ out, int cb, int b0)
{
  const int bid = blockIdx.x;
  int bl, g;
  if ((cb & 7) == 0) {
    const int xcd = bid & 7;
    const int j   = bid >> 3;
    g  = j & 31;
    bl = (j >> 5) * 8 + xcd;
  } else {
    bl = bid >> 5;
    g  = bid & 31;
  }
  const int node = g * 4 + (threadIdx.x >> 6);
  const int l    = threadIdx.x & 63;
  const int bg   = b0 + bl;

  float val = 0.f;
  if (l < 2 * KS) {
    const int kb = l >> 1, comp = l & 1;
    val = zpart[((size_t)kb * cb + bl) * NOUT + node * 2 + comp];
  }
  #pragma unroll
  for (int off = 2; off < 2 * KS; off <<= 1) val += __shfl_xor(val, off);
  const float z0 = __shfl(val, 0) + fcb[node * 2 + 0];
  const float z1 = __shfl(val, 1) + fcb[node * 2 + 1];
  const float ch = 31.f / (1.f + __expf(-3.f * z0));
  const float cw = 63.f / (1.f + __expf(-3.f * z1));

  if (l < 2)
    out[GF_SIZE + (((size_t)bg * NODES + node) << 1) + l] = l ? cw : ch;

  const float chv = fminf(fmaxf(ch, 0.f), 31.f);
  const float cwv = fminf(fmaxf(cw, 0.f), 63.f);
  const float fh = floorf(chv), fw = floorf(cwv);
  const int h0 = (int)fh, h1i = (int)ceilf(chv);
  const int w0 = (int)fw, w1i = (int)ceilf(cwv);
  const float oh = chv - fh, ow = cwv - fw;
  const ushort* xbp = xt + (size_t)bg * HW * CIN + l;
  const float v_lt = bf2f(xbp[(size_t)(h0 * WW + w0) * CIN]);
  const float v_rt = bf2f(xbp[(size_t)(h1i * WW + w0) * CIN]);
  const float v_lb = bf2f(xbp[(size_t)(h0 * WW + w1i) * CIN]);
  const float v_rb = bf2f(xbp[(size_t)(h1i * WW + w1i) * CIN]);
  const float vt = v_lt + oh * (v_rt - v_lt);
  const float vb = v_lb + oh * (v_rb - v_lb);
  out[((size_t)bg * NODES + node) * CIN + l] = vt + ow * (vb - vt);
}

// ---------------------------------------------------------------------------
extern "C" void kernel_launch(void* const* d_in, const int* in_sizes, int n_in,
                              void* d_out, int out_size, void* d_ws, size_t ws_size,
                              hipStream_t stream)
{
  (void)in_sizes; (void)n_in; (void)out_size;
  const float* x   = (const float*)d_in[0];
  const float* w11 = (const float*)d_in[1];
  const float* b11 = (const float*)d_in[2];
  const float* w12 = (const float*)d_in[3];
  const float* b12 = (const float*)d_in[4];
  const float* w21 = (const float*)d_in[5];
  const float* b21 = (const float*)d_in[6];
  const float* w22 = (const float*)d_in[7];
  const float* b22 = (const float*)d_in[8];
  const float* fcw = (const float*)d_in[9];
  const float* fcb = (const float*)d_in[10];
  float* out = (float*)d_out;
  char* wsb  = (char*)d_ws;

  // fixed: xt (134 MB) + fcw hi/lo planes (8 MB). ws_size ~= 1 GiB.
  const size_t xtBytes = (size_t)BATCH * HW * CIN * 2;
  const size_t perB    = 16384 + 16384 + (size_t)KS * NOUT * 4;   // h4 hi/lo + zpart
  const size_t fixed   = xtBytes + 2 * 4194304;
  size_t avail = ws_size > fixed ? ws_size - fixed : perB;
  size_t cbmax = avail / perB;
  int CB = (int)(cbmax < (size_t)BATCH ? cbmax : (size_t)BATCH);
  if (CB < 1) CB = 1;

  char* p = wsb;
  ushort* xtv  = (ushort*)p;  p += xtBytes;
  ushort* h4h  = (ushort*)p;  p += (size_t)CB * 16384;
  ushort* h4l  = (ushort*)p;  p += (size_t)CB * 16384;
  float*  zpv  = (float*)p;   p += (size_t)CB * KS * NOUT * 4;
  ushort* fcwh = (ushort*)p;  p += 4194304;
  ushort* fcwl = (ushort*)p;

  k_cvt_fcw<<<dim3(NOUT * KFC / (256 * 8)), 256, 0, stream>>>(fcw, fcwh, fcwl);
  k_xpose<<<dim3(8, BATCH), 256, 0, stream>>>(x, xtv);

  for (int b0 = 0; b0 < BATCH; b0 += CB) {
    const int cb = (BATCH - b0 < CB) ? (BATCH - b0) : CB;
    k_conv1234<<<dim3(cb), 1024, 0, stream>>>(xtv, w11, b11, w12, b12,
                                              w21, b21, w22, b22, h4h, h4l, b0);
    k_fc<<<dim3((cb + 63) / 64, 4, KS), 256, 0, stream>>>(h4h, h4l, fcwh, fcwl, zpv, cb);
    k_gather<<<dim3(cb * 32), 256, 0, stream>>>(xtv, zpv, fcb, out, cb, b0);
  }
}

// Round 12
// 250.557 us; speedup vs baseline: 1.0977x; 1.0977x over previous
//
#include <hip/hip_runtime.h>
#include <hip/hip_fp16.h>
#include <cstdint>

#define BATCH 512
#define CIN   64
#define HH    32
#define WW    64
#define HW    2048
#define C1    32
#define C2    16
#define C3    8
#define C4    4
#define NOUT  256
#define KFC   8192
#define NODES 128
#define KS    16                      // FC K-split
#define GF_SIZE (BATCH * NODES * CIN)

typedef __attribute__((ext_vector_type(8))) short bfrag;   // 8 bf16 (4 VGPRs)
typedef __attribute__((ext_vector_type(4))) float ffrag;   // 4 fp32 acc

__device__ __forceinline__ ushort bf_trunc(float f) { return (ushort)(__float_as_uint(f) >> 16); }
__device__ __forceinline__ float  bf_truncf(float f) { return __uint_as_float(__float_as_uint(f) & 0xffff0000u); }
__device__ __forceinline__ ushort f2bf(float f) {
  uint32_t u = __float_as_uint(f);
  return (ushort)((u + 0x7fffu + ((u >> 16) & 1u)) >> 16);
}
__device__ __forceinline__ uint32_t pack2(float a, float b) {
  return (uint32_t)f2bf(a) | ((uint32_t)f2bf(b) << 16);
}
__device__ __forceinline__ uint32_t packhi2(float a, float b) {
  return (uint32_t)bf_trunc(a) | ((uint32_t)bf_trunc(b) << 16);
}
__device__ __forceinline__ ushort f2h(float f) { return __half_as_ushort(__float2half_rn(f)); }
__device__ __forceinline__ uint32_t packh2(float a, float b) {
  return (uint32_t)f2h(a) | ((uint32_t)f2h(b) << 16);
}
__device__ __forceinline__ float h2f(uint32_t u) { return __half2float(__ushort_as_half((ushort)u)); }
__device__ __forceinline__ float bf2f(ushort u) { return __uint_as_float(((uint32_t)u) << 16); }

// ---------------------------------------------------------------------------
// K0: x NCHW fp32 -> xt NHWC bf16 (RTN), LDS-staged for coalesced stores.
// ---------------------------------------------------------------------------
__global__ __launch_bounds__(256) void k_xpose(
    const float* __restrict__ x, ushort* __restrict__ xt)
{
  __shared__ uint32_t tb[256 * 33];
  const int t  = threadIdx.x;
  const int b  = blockIdx.y;
  const int rg = blockIdx.x;                 // 4-row group, 256 px
  const float* xp = x + (size_t)b * CIN * HW + rg * 256 + t;
  #pragma unroll
  for (int j = 0; j < 32; ++j) {
    float v0 = xp[(size_t)(2 * j) * HW];
    float v1 = xp[(size_t)(2 * j + 1) * HW];
    tb[t * 33 + j] = pack2(v0, v1);
  }
  __syncthreads();
  ushort* op = xt + ((size_t)b * HW + rg * 256) * CIN;
  #pragma unroll
  for (int k = 0; k < 8; ++k) {
    const int u = k * 256 + t;
    const int p = u >> 3, q = u & 7;
    uint4 v;
    v.x = tb[p * 33 + q * 4 + 0];
    v.y = tb[p * 33 + q * 4 + 1];
    v.z = tb[p * 33 + q * 4 + 2];
    v.w = tb[p * 33 + q * 4 + 3];
    *(uint4*)(op + (size_t)u * 8) = v;
  }
}

// ---------------------------------------------------------------------------
// K1: conv1..conv4 fused, WHOLE IMAGE per block — v2, <=64-VGPR phases.
// R11 failed: hipcc clamps 1024-thread kernels to 64 VGPR; Phase B held
// ~105 live (w2 72 + ph 16) -> 180 MB spill. v2 restructure:
//  Phase A: single x-frag register reused across the two K-steps
//           (live ~ w1 32 + f 4 + acc 8 + bias 8 + addr ~8 = 60).
//  Phase B: TAP-OUTER loop — one tap's w2 frags (8) live with acc[8] (32);
//           bias2 applied after the loop; acc carries across the barrier
//           (live ~ 54). No ph registers at all.
//  Phases C1/C2 as R11 (low pressure).
// LDS: stage1 h1 [33][66][64B] = 139392; stage2 h2 65536 + h3 76032 = 141568.
// grid cb, 1024 thr (16 waves = 4 waves/SIMD).
// ---------------------------------------------------------------------------
__global__ __launch_bounds__(1024) void k_conv1234(
    const ushort* __restrict__ xt, const float* __restrict__ w11, const float* __restrict__ b11,
    const float* __restrict__ w12, const float* __restrict__ b12,
    const float* __restrict__ w21, const float* __restrict__ b21,
    const float* __restrict__ w22, const float* __restrict__ b22,
    ushort* __restrict__ h4h, ushort* __restrict__ h4l, int b0)
{
  __shared__ __align__(16) char smem[141568];
  const int tid = threadIdx.x;
  const int l   = tid & 63;
  const int wv  = tid >> 6;    // 0..15
  const int lr  = l & 15;
  const int lg  = l >> 4;
  const int bg  = b0 + blockIdx.x;
  const ushort* xtb = xt + (size_t)bg * HW * CIN;

  // init: pad cols (0,65) of rows 0..32, and full zero row 32.
  if (tid < 264) {            // pad cols: 33 rows x 2 cols x 64 B
    int row = tid >> 3, rem = tid & 7;
    int colb = (rem < 4) ? 0 : 65, q = rem & 3;
    *(uint4*)(smem + ((row * 66 + colb) << 6) + q * 16) = uint4{0u, 0u, 0u, 0u};
  } else if (tid < 528) {     // zero row 32: 66 cols x 64 B
    int idx = tid - 264;
    int col = idx >> 2, q = idx & 3;
    *(uint4*)(smem + ((32 * 66 + col) << 6) + q * 16) = uint4{0u, 0u, 0u, 0u};
  }

  // W1 fragments (hi/lo split keeps W fp32-grade)
  bfrag w1h[2][2], w1l[2][2];
  #pragma unroll
  for (int m = 0; m < 2; ++m) {
    #pragma unroll
    for (int ks = 0; ks < 2; ++ks) {
      const float* wp = w11 + (m * 16 + lr) * 64 + ks * 32 + lg * 8;
      #pragma unroll
      for (int e = 0; e < 8; ++e) {
        float v = wp[e];
        w1h[m][ks][e] = (short)bf_trunc(v);
        w1l[m][ks][e] = (short)f2bf(v - bf_truncf(v));
      }
    }
  }
  float bias1[2][4];
  #pragma unroll
  for (int m = 0; m < 2; ++m) {
    #pragma unroll
    for (int r = 0; r < 4; ++r) bias1[m][r] = b11[m * 16 + lg * 4 + r];
  }

  // ---- Phase A: conv1 -> h1 LDS. 128 tiles (32 rows x 4 col-tiles), 8/wave.
  // One x-frag register, reused across the two K-steps (register-frugal).
  #pragma unroll 2
  for (int i = 0; i < 8; ++i) {
    const int nt   = wv * 8 + i;
    const int ry   = nt >> 2;             // 0..31, all valid
    const int col0 = (nt & 3) << 4;
    const ushort* xp = xtb + (size_t)(ry * WW + col0 + lr) * CIN + lg * 8;
    ffrag a0 = {0.f, 0.f, 0.f, 0.f}, a1 = {0.f, 0.f, 0.f, 0.f};
    {
      bfrag f = *(const bfrag*)xp;                       // K-step 0
      a0 = __builtin_amdgcn_mfma_f32_16x16x32_bf16(w1h[0][0], f, a0, 0, 0, 0);
      a0 = __builtin_amdgcn_mfma_f32_16x16x32_bf16(w1l[0][0], f, a0, 0, 0, 0);
      a1 = __builtin_amdgcn_mfma_f32_16x16x32_bf16(w1h[1][0], f, a1, 0, 0, 0);
      a1 = __builtin_amdgcn_mfma_f32_16x16x32_bf16(w1l[1][0], f, a1, 0, 0, 0);
      f = *(const bfrag*)(xp + 32);                      // K-step 1
      a0 = __builtin_amdgcn_mfma_f32_16x16x32_bf16(w1h[0][1], f, a0, 0, 0, 0);
      a0 = __builtin_amdgcn_mfma_f32_16x16x32_bf16(w1l[0][1], f, a0, 0, 0, 0);
      a1 = __builtin_amdgcn_mfma_f32_16x16x32_bf16(w1h[1][1], f, a1, 0, 0, 0);
      a1 = __builtin_amdgcn_mfma_f32_16x16x32_bf16(w1l[1][1], f, a1, 0, 0, 0);
    }
    const int colb = col0 + 1 + lr;
    #pragma unroll
    for (int m = 0; m < 2; ++m) {
      float v0 = fmaxf((m ? a1[0] : a0[0]) + bias1[m][0], 0.f);
      float v1 = fmaxf((m ? a1[1] : a0[1]) + bias1[m][1], 0.f);
      float v2 = fmaxf((m ? a1[2] : a0[2]) + bias1[m][2], 0.f);
      float v3 = fmaxf((m ? a1[3] : a0[3]) + bias1[m][3], 0.f);
      int chunk = (m * 2 + (lg >> 1)) ^ ((colb >> 1) & 3);
      char* dst = smem + ((ry * 66 + colb) << 6) + (chunk << 4) + (lg & 1) * 8;
      *(uint2*)dst = uint2{pack2(v0, v1), pack2(v2, v3)};
    }
  }
  __syncthreads();

  // ---- Phase B: conv2, TAP-OUTER. acc[8] accumulates all 8 tiles/wave.
  ffrag acc[8] = {};
  #pragma unroll
  for (int t = 0; t < 9; ++t) {
    bfrag wh, wl;
    {
      const float* wp = w12 + lr * 288 + t;
      #pragma unroll
      for (int e = 0; e < 8; ++e) {
        float v = wp[(lg * 8 + e) * 9];
        wh[e] = (short)bf_trunc(v);
        wl[e] = (short)f2bf(v - bf_truncf(v));
      }
    }
    const int ky = t / 3, kx = t - ky * 3;
    #pragma unroll
    for (int i = 0; i < 8; ++i) {
      const int nt   = wv * 8 + i;
      const int hy   = nt >> 2;           // 0..31
      const int col0 = (nt & 3) << 4;
      const int yv   = hy - 1 + ky;
      const int row  = ((unsigned)yv < 32u) ? yv : 32;   // zero row
      const int colb  = col0 + lr + kx;
      const int chunk = lg ^ ((colb >> 1) & 3);
      const bfrag hv = *(const bfrag*)(smem + ((row * 66 + colb) << 6) + (chunk << 4));
      acc[i] = __builtin_amdgcn_mfma_f32_16x16x32_bf16(wh, hv, acc[i], 0, 0, 0);
      acc[i] = __builtin_amdgcn_mfma_f32_16x16x32_bf16(wl, hv, acc[i], 0, 0, 0);
    }
  }
  __syncthreads();   // all h1 reads done; smem reusable

  // bias + pack + h2 -> LDS [32 rows][64 px][16 ch fp16] = 65536 B.
  {
    float bias2[4];
    #pragma unroll
    for (int r = 0; r < 4; ++r) bias2[r] = b12[lg * 4 + r];
    #pragma unroll
    for (int i = 0; i < 8; ++i) {
      const int nt  = wv * 8 + i;
      const int hy  = nt >> 2;
      const int col = ((nt & 3) << 4) + lr;
      uint32_t p0 = packh2(fmaxf(acc[i][0] + bias2[0], 0.f), fmaxf(acc[i][1] + bias2[1], 0.f));
      uint32_t p1 = packh2(fmaxf(acc[i][2] + bias2[2], 0.f), fmaxf(acc[i][3] + bias2[3], 0.f));
      *(uint2*)(smem + ((hy * 64 + col) << 5) + lg * 8) = uint2{p0, p1};
    }
  }
  __syncthreads();

  // ---- Phase C1: conv3 (1x1, 16->8) -> h3 f32 LDS [33][64][9] @ +65536
  float* h3b = (float*)(smem + 65536);
  if (tid < 576) {           // zero row 32: 64 px x 9 floats
    const int px = tid / 9, c = tid - px * 9;
    h3b[(32 * 64 + px) * 9 + c] = 0.f;
  }
  #pragma unroll
  for (int it = 0; it < 2; ++it) {
    const int p  = it * 1024 + tid;
    const int ry = p >> 6, wc = p & 63;
    const uint4 ua = *(const uint4*)(smem + ((ry * 64 + wc) << 5));
    const uint4 ub = *(const uint4*)(smem + ((ry * 64 + wc) << 5) + 16);
    uint32_t uw[8] = {ua.x, ua.y, ua.z, ua.w, ub.x, ub.y, ub.z, ub.w};
    float xv[16];
    #pragma unroll
    for (int j = 0; j < 8; ++j) {
      xv[2*j]   = h2f(uw[j] & 0xffffu);
      xv[2*j+1] = h2f(uw[j] >> 16);
    }
    float acc3[C3];
    #pragma unroll
    for (int o = 0; o < C3; ++o) acc3[o] = b21[o];
    #pragma unroll
    for (int c = 0; c < 16; ++c) {
      float v = xv[c];
      #pragma unroll
      for (int o = 0; o < C3; ++o)
        acc3[o] = fmaf(v, w21[o * 16 + c], acc3[o]);   // uniform -> s_load
    }
    float* hd = h3b + (ry * 64 + wc) * 9;
    #pragma unroll
    for (int c = 0; c < C3; ++c) hd[c] = fmaxf(acc3[c], 0.f);
  }
  __syncthreads();

  // ---- Phase C2: conv4 (3x3, 8->4) -> h4 bf16 hi/lo global.
  #pragma unroll
  for (int it = 0; it < 2; ++it) {
    const int p  = it * 1024 + tid;
    const int yl = p >> 6, wc = p & 63;
    float acc4[C4] = {b22[0], b22[1], b22[2], b22[3]};
    #pragma unroll
    for (int ky = 0; ky < 3; ++ky) {
      const int yv  = yl - 1 + ky;
      const int row = ((unsigned)yv < 32u) ? yv : 32;
      #pragma unroll
      for (int kx = 0; kx < 3; ++kx) {
        const int wcc = wc + kx - 1;
        if (wcc < 0 || wcc >= WW) continue;
        const float* hb = h3b + (row * 64 + wcc) * 9;
        const int tap = ky * 3 + kx;
        #pragma unroll
        for (int c = 0; c < C3; ++c) {
          float v = hb[c];
          #pragma unroll
          for (int o = 0; o < C4; ++o)
            acc4[o] = fmaf(v, w22[(o * 8 + c) * 9 + tap], acc4[o]);  // s_load
        }
      }
    }
    const size_t base = (size_t)blockIdx.x * KFC + yl * WW + wc;
    #pragma unroll
    for (int o = 0; o < C4; ++o) {
      float v = fmaxf(acc4[o], 0.f);
      h4h[base + (size_t)o * HW] = bf_trunc(v);
      h4l[base + (size_t)o * HW] = f2bf(v - bf_truncf(v));
    }
  }
}

// ---------------------------------------------------------------------------
// K2b: fcw fp32 -> bf16 hi/lo planes (once per launch, deterministic)
// ---------------------------------------------------------------------------
__global__ __launch_bounds__(256) void k_cvt_fcw(
    const float* __restrict__ w, ushort* __restrict__ hi, ushort* __restrict__ lo)
{
  const int i = (blockIdx.x * 256 + threadIdx.x) * 8;
  const float4 a = *(const float4*)(w + i);
  const float4 b = *(const float4*)(w + i + 4);
  uint4 hv, lv;
  hv.x = packhi2(a.x, a.y); hv.y = packhi2(a.z, a.w);
  hv.z = packhi2(b.x, b.y); hv.w = packhi2(b.z, b.w);
  lv.x = pack2(a.x - bf_truncf(a.x), a.y - bf_truncf(a.y));
  lv.y = pack2(a.z - bf_truncf(a.z), a.w - bf_truncf(a.w));
  lv.z = pack2(b.x - bf_truncf(b.x), b.y - bf_truncf(b.y));
  lv.w = pack2(b.z - bf_truncf(b.z), b.w - bf_truncf(b.w));
  *(uint4*)(hi + i) = hv;
  *(uint4*)(lo + i) = lv;
}

// ---------------------------------------------------------------------------
// K3: FC GEMM, MFMA bf16 3-product (hi/lo), K split KS-way, deterministic.
// ---------------------------------------------------------------------------
__global__ __launch_bounds__(256) void k_fc(
    const ushort* __restrict__ Ahp, const ushort* __restrict__ Alp,
    const ushort* __restrict__ Bhp, const ushort* __restrict__ Blp,
    float* __restrict__ zpart, int cb)
{
  const int tid = threadIdx.x;
  const int l   = tid & 63;
  const int wv  = tid >> 6;
  const int lr  = l & 15;
  const int lg  = l >> 4;
  const int m0  = blockIdx.x * 64 + (wv >> 1) * 32;
  const int n0  = blockIdx.y * 64 + (wv & 1) * 32;
  const int k0  = blockIdx.z * (KFC / KS);     // 512 per split

  int mrow[2], nrow[2];
  #pragma unroll
  for (int t = 0; t < 2; ++t) {
    int m = m0 + t * 16 + lr;
    mrow[t] = m < cb ? m : cb - 1;             // clamp; masked at write
    nrow[t] = n0 + t * 16 + lr;
  }
  ffrag acc[2][2] = {};

  #pragma unroll 1
  for (int kc = 0; kc < (KFC / KS) / 32; ++kc) {
    const int k = k0 + kc * 32 + lg * 8;
    bfrag ah[2], al[2], bh[2], bl[2];
    #pragma unroll
    for (int t = 0; t < 2; ++t) {
      ah[t] = *(const bfrag*)(Ahp + (size_t)mrow[t] * KFC + k);
      al[t] = *(const bfrag*)(Alp + (size_t)mrow[t] * KFC + k);
      bh[t] = *(const bfrag*)(Bhp + (size_t)nrow[t] * KFC + k);
      bl[t] = *(const bfrag*)(Blp + (size_t)nrow[t] * KFC + k);
    }
    #pragma unroll
    for (int mt = 0; mt < 2; ++mt) {
      #pragma unroll
      for (int nt = 0; nt < 2; ++nt) {
        acc[mt][nt] = __builtin_amdgcn_mfma_f32_16x16x32_bf16(ah[mt], bh[nt], acc[mt][nt], 0, 0, 0);
        acc[mt][nt] = __builtin_amdgcn_mfma_f32_16x16x32_bf16(ah[mt], bl[nt], acc[mt][nt], 0, 0, 0);
        acc[mt][nt] = __builtin_amdgcn_mfma_f32_16x16x32_bf16(al[mt], bh[nt], acc[mt][nt], 0, 0, 0);
      }
    }
  }

  #pragma unroll
  for (int mt = 0; mt < 2; ++mt) {
    #pragma unroll
    for (int r = 0; r < 4; ++r) {
      const int m = m0 + mt * 16 + lg * 4 + r;
      if (m < cb) {
        #pragma unroll
        for (int nt = 0; nt < 2; ++nt)
          zpart[((size_t)blockIdx.z * cb + m) * NOUT + n0 + nt * 16 + lr] = acc[mt][nt][r];
      }
    }
  }
}

// ---------------------------------------------------------------------------
// K5: fused coord + bilinear gather reading xt (NHWC bf16), XCD-grouped.
// ---------------------------------------------------------------------------
__global__ __launch_bounds__(256) void k_gather(
    const ushort* __restrict__ xt, const float* __restrict__ zpart,
    const float* __restrict__ fcb, float* __restrict__ out, int cb, int b0)
{
  const int bid = blockIdx.x;
  int bl, g;
  if ((cb & 7) == 0) {
    const int xcd = bid & 7;
    const int j   = bid >> 3;
    g  = j & 31;
    bl = (j >> 5) * 8 + xcd;
  } else {
    bl = bid >> 5;
    g  = bid & 31;
  }
  const int node = g * 4 + (threadIdx.x >> 6);
  const int l    = threadIdx.x & 63;
  const int bg   = b0 + bl;

  float val = 0.f;
  if (l < 2 * KS) {
    const int kb = l >> 1, comp = l & 1;
    val = zpart[((size_t)kb * cb + bl) * NOUT + node * 2 + comp];
  }
  #pragma unroll
  for (int off = 2; off < 2 * KS; off <<= 1) val += __shfl_xor(val, off);
  const float z0 = __shfl(val, 0) + fcb[node * 2 + 0];
  const float z1 = __shfl(val, 1) + fcb[node * 2 + 1];
  const float ch = 31.f / (1.f + __expf(-3.f * z0));
  const float cw = 63.f / (1.f + __expf(-3.f * z1));

  if (l < 2)
    out[GF_SIZE + (((size_t)bg * NODES + node) << 1) + l] = l ? cw : ch;

  const float chv = fminf(fmaxf(ch, 0.f), 31.f);
  const float cwv = fminf(fmaxf(cw, 0.f), 63.f);
  const float fh = floorf(chv), fw = floorf(cwv);
  const int h0 = (int)fh, h1i = (int)ceilf(chv);
  const int w0 = (int)fw, w1i = (int)ceilf(cwv);
  const float oh = chv - fh, ow = cwv - fw;
  const ushort* xbp = xt + (size_t)bg * HW * CIN + l;
  const float v_lt = bf2f(xbp[(size_t)(h0 * WW + w0) * CIN]);
  const float v_rt = bf2f(xbp[(size_t)(h1i * WW + w0) * CIN]);
  const float v_lb = bf2f(xbp[(size_t)(h0 * WW + w1i) * CIN]);
  const float v_rb = bf2f(xbp[(size_t)(h1i * WW + w1i) * CIN]);
  const float vt = v_lt + oh * (v_rt - v_lt);
  const float vb = v_lb + oh * (v_rb - v_lb);
  out[((size_t)bg * NODES + node) * CIN + l] = vt + ow * (vb - vt);
}

// ---------------------------------------------------------------------------
extern "C" void kernel_launch(void* const* d_in, const int* in_sizes, int n_in,
                              void* d_out, int out_size, void* d_ws, size_t ws_size,
                              hipStream_t stream)
{
  (void)in_sizes; (void)n_in; (void)out_size;
  const float* x   = (const float*)d_in[0];
  const float* w11 = (const float*)d_in[1];
  const float* b11 = (const float*)d_in[2];
  const float* w12 = (const float*)d_in[3];
  const float* b12 = (const float*)d_in[4];
  const float* w21 = (const float*)d_in[5];
  const float* b21 = (const float*)d_in[6];
  const float* w22 = (const float*)d_in[7];
  const float* b22 = (const float*)d_in[8];
  const float* fcw = (const float*)d_in[9];
  const float* fcb = (const float*)d_in[10];
  float* out = (float*)d_out;
  char* wsb  = (char*)d_ws;

  // fixed: xt (134 MB) + fcw hi/lo planes (8 MB). ws_size ~= 1 GiB.
  const size_t xtBytes = (size_t)BATCH * HW * CIN * 2;
  const size_t perB    = 16384 + 16384 + (size_t)KS * NOUT * 4;   // h4 hi/lo + zpart
  const size_t fixed   = xtBytes + 2 * 4194304;
  size_t avail = ws_size > fixed ? ws_size - fixed : perB;
  size_t cbmax = avail / perB;
  int CB = (int)(cbmax < (size_t)BATCH ? cbmax : (size_t)BATCH);
  if (CB < 1) CB = 1;

  char* p = wsb;
  ushort* xtv  = (ushort*)p;  p += xtBytes;
  ushort* h4h  = (ushort*)p;  p += (size_t)CB * 16384;
  ushort* h4l  = (ushort*)p;  p += (size_t)CB * 16384;
  float*  zpv  = (float*)p;   p += (size_t)CB * KS * NOUT * 4;
  ushort* fcwh = (ushort*)p;  p += 4194304;
  ushort* fcwl = (ushort*)p;

  k_cvt_fcw<<<dim3(NOUT * KFC / (256 * 8)), 256, 0, stream>>>(fcw, fcwh, fcwl);
  k_xpose<<<dim3(8, BATCH), 256, 0, stream>>>(x, xtv);

  for (int b0 = 0; b0 < BATCH; b0 += CB) {
    const int cb = (BATCH - b0 < CB) ? (BATCH - b0) : CB;
    k_conv1234<<<dim3(cb), 1024, 0, stream>>>(xtv, w11, b11, w12, b12,
                                              w21, b21, w22, b22, h4h, h4l, b0);
    k_fc<<<dim3((cb + 63) / 64, 4, KS), 256, 0, stream>>>(h4h, h4l, fcwh, fcwl, zpv, cb);
    k_gather<<<dim3(cb * 32), 256, 0, stream>>>(xtv, zpv, fcb, out, cb, b0);
  }
}

// Round 13
// 223.923 us; speedup vs baseline: 1.2282x; 1.1189x over previous
//
#include <hip/hip_runtime.h>
#include <hip/hip_fp16.h>
#include <cstdint>

#define BATCH 512
#define CIN   64
#define HH    32
#define WW    64
#define HW    2048
#define C1    32
#define C2    16
#define C3    8
#define C4    4
#define NOUT  256
#define KFC   8192
#define NODES 128
#define KS    16                      // FC K-split
#define GF_SIZE (BATCH * NODES * CIN)

typedef __attribute__((ext_vector_type(8))) short bfrag;   // 8 bf16 (4 VGPRs)
typedef __attribute__((ext_vector_type(4))) float ffrag;   // 4 fp32 acc

__device__ __forceinline__ ushort bf_trunc(float f) { return (ushort)(__float_as_uint(f) >> 16); }
__device__ __forceinline__ float  bf_truncf(float f) { return __uint_as_float(__float_as_uint(f) & 0xffff0000u); }
__device__ __forceinline__ ushort f2bf(float f) {
  uint32_t u = __float_as_uint(f);
  return (ushort)((u + 0x7fffu + ((u >> 16) & 1u)) >> 16);
}
__device__ __forceinline__ uint32_t pack2(float a, float b) {
  return (uint32_t)f2bf(a) | ((uint32_t)f2bf(b) << 16);
}
__device__ __forceinline__ uint32_t packhi2(float a, float b) {
  return (uint32_t)bf_trunc(a) | ((uint32_t)bf_trunc(b) << 16);
}
__device__ __forceinline__ ushort f2h(float f) { return __half_as_ushort(__float2half_rn(f)); }
__device__ __forceinline__ uint32_t packh2(float a, float b) {
  return (uint32_t)f2h(a) | ((uint32_t)f2h(b) << 16);
}
__device__ __forceinline__ float h2f(uint32_t u) { return __half2float(__ushort_as_half((ushort)u)); }
__device__ __forceinline__ float bf2f(ushort u) { return __uint_as_float(((uint32_t)u) << 16); }

__device__ __forceinline__ bfrag ld_frag4(const uint32_t* tp) {
  union { uint32_t u[4]; bfrag b; } c;
  c.u[0] = tp[0]; c.u[1] = tp[1]; c.u[2] = tp[2]; c.u[3] = tp[3];
  return c.b;
}

// ---------------------------------------------------------------------------
// K0 "front": xpose + conv1 + cvt_fcw, one launch.
//  by <  BATCH : block = (image, 4 rows). Stage x coalesced into LDS
//                (bf16-pair packed, [256 px][33 u32]); write xt (coalesced
//                uint4, R9-proven); THEN conv1 via MFMA straight from the
//                staged LDS (1x1 conv -> no halo) -> h1 px-major bf16 global.
//  by >= BATCH : fcw fp32 -> bf16 hi/lo planes (the old k_cvt_fcw).
// ---------------------------------------------------------------------------
__global__ __launch_bounds__(256) void k_front(
    const float* __restrict__ x, const float* __restrict__ w11, const float* __restrict__ b11,
    const float* __restrict__ fcw, ushort* __restrict__ fcwh, ushort* __restrict__ fcwl,
    ushort* __restrict__ xt, ushort* __restrict__ h1g)
{
  if (blockIdx.y >= BATCH) {   // ---- cvt_fcw branch (1024 block-equivalents)
    const int chunk = (blockIdx.y - BATCH) * 8 + blockIdx.x;
    const int i = (chunk * 256 + threadIdx.x) * 8;
    const float4 a = *(const float4*)(fcw + i);
    const float4 b = *(const float4*)(fcw + i + 4);
    uint4 hv, lv;
    hv.x = packhi2(a.x, a.y); hv.y = packhi2(a.z, a.w);
    hv.z = packhi2(b.x, b.y); hv.w = packhi2(b.z, b.w);
    lv.x = pack2(a.x - bf_truncf(a.x), a.y - bf_truncf(a.y));
    lv.y = pack2(a.z - bf_truncf(a.z), a.w - bf_truncf(a.w));
    lv.z = pack2(b.x - bf_truncf(b.x), b.y - bf_truncf(b.y));
    lv.w = pack2(b.z - bf_truncf(b.z), b.w - bf_truncf(b.w));
    *(uint4*)(fcwh + i) = hv;
    *(uint4*)(fcwl + i) = lv;
    return;
  }

  __shared__ uint32_t tb[256 * 33];
  const int t  = threadIdx.x;
  const int b  = blockIdx.y;
  const int rg = blockIdx.x;                 // 4-row group, 256 px
  {
    const float* xp = x + (size_t)b * CIN * HW + rg * 256 + t;
    #pragma unroll
    for (int j = 0; j < 32; ++j) {
      float v0 = xp[(size_t)(2 * j) * HW];
      float v1 = xp[(size_t)(2 * j + 1) * HW];
      tb[t * 33 + j] = pack2(v0, v1);
    }
  }
  __syncthreads();

  // xt stores: consecutive uint4 per consecutive lane = 4 KB/wave-inst.
  {
    ushort* op = xt + ((size_t)b * HW + rg * 256) * CIN;
    #pragma unroll
    for (int k = 0; k < 8; ++k) {
      const int u = k * 256 + t;
      const int p = u >> 3, q = u & 7;
      uint4 v;
      v.x = tb[p * 33 + q * 4 + 0];
      v.y = tb[p * 33 + q * 4 + 1];
      v.z = tb[p * 33 + q * 4 + 2];
      v.w = tb[p * 33 + q * 4 + 3];
      *(uint4*)(op + (size_t)u * 8) = v;
    }
  }

  // conv1 (1x1, 64->32) via MFMA from staged LDS. 16 px-tiles, 4/wave.
  const int l  = t & 63;
  const int wv = t >> 6;
  const int lr = l & 15;
  const int lg = l >> 4;
  bfrag w1h[2][2], w1l[2][2];
  #pragma unroll
  for (int m = 0; m < 2; ++m) {
    #pragma unroll
    for (int ks = 0; ks < 2; ++ks) {
      const float* wp = w11 + (m * 16 + lr) * 64 + ks * 32 + lg * 8;
      #pragma unroll
      for (int e = 0; e < 8; ++e) {
        float v = wp[e];
        w1h[m][ks][e] = (short)bf_trunc(v);
        w1l[m][ks][e] = (short)f2bf(v - bf_truncf(v));
      }
    }
  }
  float bias1[2][4];
  #pragma unroll
  for (int m = 0; m < 2; ++m) {
    #pragma unroll
    for (int r = 0; r < 4; ++r) bias1[m][r] = b11[m * 16 + lg * 4 + r];
  }

  #pragma unroll
  for (int i = 0; i < 4; ++i) {
    const int pxl = (wv * 4 + i) * 16 + lr;            // 0..255
    const bfrag f0 = ld_frag4(&tb[pxl * 33 + lg * 4]);        // ch lg*8..+7
    const bfrag f1 = ld_frag4(&tb[pxl * 33 + 16 + lg * 4]);   // ch 32+lg*8..+7
    ffrag a0 = {0.f, 0.f, 0.f, 0.f}, a1 = {0.f, 0.f, 0.f, 0.f};
    a0 = __builtin_amdgcn_mfma_f32_16x16x32_bf16(w1h[0][0], f0, a0, 0, 0, 0);
    a0 = __builtin_amdgcn_mfma_f32_16x16x32_bf16(w1l[0][0], f0, a0, 0, 0, 0);
    a0 = __builtin_amdgcn_mfma_f32_16x16x32_bf16(w1h[0][1], f1, a0, 0, 0, 0);
    a0 = __builtin_amdgcn_mfma_f32_16x16x32_bf16(w1l[0][1], f1, a0, 0, 0, 0);
    a1 = __builtin_amdgcn_mfma_f32_16x16x32_bf16(w1h[1][0], f0, a1, 0, 0, 0);
    a1 = __builtin_amdgcn_mfma_f32_16x16x32_bf16(w1l[1][0], f0, a1, 0, 0, 0);
    a1 = __builtin_amdgcn_mfma_f32_16x16x32_bf16(w1h[1][1], f1, a1, 0, 0, 0);
    a1 = __builtin_amdgcn_mfma_f32_16x16x32_bf16(w1l[1][1], f1, a1, 0, 0, 0);
    ushort* hp = h1g + ((size_t)b * HW + rg * 256 + pxl) * C1;
    #pragma unroll
    for (int m = 0; m < 2; ++m) {
      float v0 = fmaxf((m ? a1[0] : a0[0]) + bias1[m][0], 0.f);
      float v1 = fmaxf((m ? a1[1] : a0[1]) + bias1[m][1], 0.f);
      float v2 = fmaxf((m ? a1[2] : a0[2]) + bias1[m][2], 0.f);
      float v3 = fmaxf((m ? a1[3] : a0[3]) + bias1[m][3], 0.f);
      *(uint2*)(hp + m * 16 + lg * 4) = uint2{pack2(v0, v1), pack2(v2, v3)};
    }
  }
}

// ---------------------------------------------------------------------------
// K1: conv2+conv3+conv4 fused (R10-proven structure; Phase A replaced by a
// coalesced h1 load). 8 output rows/block, grid (4, cb), 256 thr.
//  Load: h1 rows r0-2..r0+9 (12 rows, OOB->0) -> LDS [12][66][64B] in the
//        SAME swizzled layout R10's Phase B expects. 50688 B -> 3 blk/CU.
//  Phase B: conv2 (MFMA, 9 taps) -> h2 fp16 in regs (10 rows).
//  Phase C1/C2: conv3 -> h3 LDS, conv4 -> h4 bf16 hi/lo global. (R10 code.)
// ---------------------------------------------------------------------------
__global__ __launch_bounds__(256) void k_conv234(
    const ushort* __restrict__ h1g, const float* __restrict__ w12, const float* __restrict__ b12,
    const float* __restrict__ w21, const float* __restrict__ b21,
    const float* __restrict__ w22, const float* __restrict__ b22,
    ushort* __restrict__ h4h, ushort* __restrict__ h4l, int b0)
{
  __shared__ __align__(16) char smem[12 * 66 * 64];   // 50688 B
  const int tid = threadIdx.x;
  const int l   = tid & 63;
  const int wv  = tid >> 6;    // 0..3
  const int lr  = l & 15;
  const int lg  = l >> 4;
  const int r0  = blockIdx.x * 8;
  const int bg  = b0 + blockIdx.y;

  // zero padded cols (colb 0 and 65) of all 12 rows
  if (tid < 192) {
    int row = tid >> 4, half = (tid >> 3) & 1, q = tid & 7;
    int cell = row * 66 + (half ? 65 : 0);
    *(uint2*)(smem + (cell << 6) + q * 8) = uint2{0u, 0u};
  }
  __syncthreads();   // pad writes before bulk loads touch neighbors? (cheap)

  // h1 rows r0-2..r0+9 -> LDS (swizzled). One row per 256-thread pass.
  {
    const int px = tid >> 2, q = tid & 3;        // q = logical 8-ch group
    const int colb  = px + 1;
    const int chunk = q ^ ((colb >> 1) & 3);
    #pragma unroll
    for (int ry = 0; ry < 12; ++ry) {
      const int y = r0 - 2 + ry;
      uint4 v = uint4{0u, 0u, 0u, 0u};
      if (y >= 0 && y < HH)
        v = *(const uint4*)(h1g + ((size_t)bg * HW + y * WW + px) * C1 + q * 8);
      *(uint4*)(smem + ((ry * 66 + colb) << 6) + (chunk << 4)) = v;
    }
  }
  __syncthreads();

  // W2 fragments from global.
  bfrag w2h[9], w2l[9];
  #pragma unroll
  for (int t = 0; t < 9; ++t) {
    const float* wp = w12 + lr * 288 + t;
    #pragma unroll
    for (int e = 0; e < 8; ++e) {
      float v = wp[(lg * 8 + e) * 9];
      w2h[t][e] = (short)bf_trunc(v);
      w2l[t][e] = (short)f2bf(v - bf_truncf(v));
    }
  }
  float bias2[4];
  #pragma unroll
  for (int r = 0; r < 4; ++r) bias2[r] = b12[lg * 4 + r];

  // Phase B: conv2 -> h2 fp16 in regs. 40 tiles (10 rows x 4), 10/wave.
  uint32_t ph0[10], ph1[10];
  #pragma unroll
  for (int i = 0; i < 10; ++i) {
    const int nt   = wv * 10 + i;
    const int hryo = nt >> 2;             // 0..9
    const int col0 = (nt & 3) << 4;
    ffrag acc = {0.f, 0.f, 0.f, 0.f};
    #pragma unroll
    for (int ky = 0; ky < 3; ++ky) {
      const int row = hryo + ky;
      #pragma unroll
      for (int kx = 0; kx < 3; ++kx) {
        const int colb  = col0 + lr + kx;
        const int chunk = lg ^ ((colb >> 1) & 3);
        const bfrag hv = *(const bfrag*)(smem + ((row * 66 + colb) << 6) + (chunk << 4));
        acc = __builtin_amdgcn_mfma_f32_16x16x32_bf16(w2h[ky * 3 + kx], hv, acc, 0, 0, 0);
        acc = __builtin_amdgcn_mfma_f32_16x16x32_bf16(w2l[ky * 3 + kx], hv, acc, 0, 0, 0);
      }
    }
    ph0[i] = packh2(fmaxf(acc[0] + bias2[0], 0.f), fmaxf(acc[1] + bias2[1], 0.f));
    ph1[i] = packh2(fmaxf(acc[2] + bias2[2], 0.f), fmaxf(acc[3] + bias2[3], 0.f));
  }
  __syncthreads();   // all h1 reads done; smem reusable

  // h2 regs -> LDS: [10 rows][64 px][16 ch fp16] = 20480 B at smem base.
  #pragma unroll
  for (int i = 0; i < 10; ++i) {
    const int nt   = wv * 10 + i;
    const int hryo = nt >> 2;
    const int col  = ((nt & 3) << 4) + lr;
    *(uint2*)(smem + ((hryo * 64 + col) << 5) + lg * 8) = uint2{ph0[i], ph1[i]};
  }
  __syncthreads();

  // Phase C1: conv3 (1x1, 16->8) -> h3 fp32 LDS [10][64][9] @ +20480.
  float* h3b = (float*)(smem + 20480);
  for (int p = tid; p < 640; p += 256) {
    const int ry = p >> 6, wc = p & 63;
    const int y  = r0 - 1 + ry;
    float* hd = h3b + (ry * 64 + wc) * 9;
    if (y >= 0 && y < HH) {
      const uint4 ua = *(const uint4*)(smem + ((ry * 64 + wc) << 5));
      const uint4 ub = *(const uint4*)(smem + ((ry * 64 + wc) << 5) + 16);
      uint32_t uw[8] = {ua.x, ua.y, ua.z, ua.w, ub.x, ub.y, ub.z, ub.w};
      float xv[16];
      #pragma unroll
      for (int j = 0; j < 8; ++j) {
        xv[2*j]   = h2f(uw[j] & 0xffffu);
        xv[2*j+1] = h2f(uw[j] >> 16);
      }
      float acc[C3];
      #pragma unroll
      for (int o = 0; o < C3; ++o) acc[o] = b21[o];
      #pragma unroll
      for (int c = 0; c < 16; ++c) {
        float v = xv[c];
        #pragma unroll
        for (int o = 0; o < C3; ++o)
          acc[o] = fmaf(v, w21[o * 16 + c], acc[o]);   // uniform -> s_load
      }
      #pragma unroll
      for (int c = 0; c < C3; ++c) hd[c] = fmaxf(acc[c], 0.f);
    } else {
      #pragma unroll
      for (int c = 0; c < C3; ++c) hd[c] = 0.f;
    }
  }
  __syncthreads();

  // Phase C2: conv4 (3x3, 8->4) -> h4 bf16 hi/lo global.
  for (int p = tid; p < 512; p += 256) {
    const int yl = p >> 6, wc = p & 63, ry = yl + 1;
    float acc[C4] = {b22[0], b22[1], b22[2], b22[3]};
    #pragma unroll
    for (int ky = 0; ky < 3; ++ky) {
      #pragma unroll
      for (int kx = 0; kx < 3; ++kx) {
        const int wcc = wc + kx - 1;
        if (wcc < 0 || wcc >= WW) continue;
        const float* hb = h3b + ((ry + ky - 1) * 64 + wcc) * 9;
        const int tap = ky * 3 + kx;
        #pragma unroll
        for (int c = 0; c < C3; ++c) {
          float v = hb[c];
          #pragma unroll
          for (int o = 0; o < C4; ++o)
            acc[o] = fmaf(v, w22[(o * 8 + c) * 9 + tap], acc[o]);  // s_load
        }
      }
    }
    const size_t base = (size_t)blockIdx.y * KFC + (r0 + yl) * WW + wc;
    #pragma unroll
    for (int o = 0; o < C4; ++o) {
      float v = fmaxf(acc[o], 0.f);
      h4h[base + (size_t)o * HW] = bf_trunc(v);
      h4l[base + (size_t)o * HW] = f2bf(v - bf_truncf(v));
    }
  }
}

// ---------------------------------------------------------------------------
// K3: FC GEMM, MFMA bf16 3-product (hi/lo), K split KS-way, deterministic.
// ---------------------------------------------------------------------------
__global__ __launch_bounds__(256) void k_fc(
    const ushort* __restrict__ Ahp, const ushort* __restrict__ Alp,
    const ushort* __restrict__ Bhp, const ushort* __restrict__ Blp,
    float* __restrict__ zpart, int cb)
{
  const int tid = threadIdx.x;
  const int l   = tid & 63;
  const int wv  = tid >> 6;
  const int lr  = l & 15;
  const int lg  = l >> 4;
  const int m0  = blockIdx.x * 64 + (wv >> 1) * 32;
  const int n0  = blockIdx.y * 64 + (wv & 1) * 32;
  const int k0  = blockIdx.z * (KFC / KS);     // 512 per split

  int mrow[2], nrow[2];
  #pragma unroll
  for (int t = 0; t < 2; ++t) {
    int m = m0 + t * 16 + lr;
    mrow[t] = m < cb ? m : cb - 1;             // clamp; masked at write
    nrow[t] = n0 + t * 16 + lr;
  }
  ffrag acc[2][2] = {};

  #pragma unroll 1
  for (int kc = 0; kc < (KFC / KS) / 32; ++kc) {
    const int k = k0 + kc * 32 + lg * 8;
    bfrag ah[2], al[2], bh[2], bl[2];
    #pragma unroll
    for (int t = 0; t < 2; ++t) {
      ah[t] = *(const bfrag*)(Ahp + (size_t)mrow[t] * KFC + k);
      al[t] = *(const bfrag*)(Alp + (size_t)mrow[t] * KFC + k);
      bh[t] = *(const bfrag*)(Bhp + (size_t)nrow[t] * KFC + k);
      bl[t] = *(const bfrag*)(Blp + (size_t)nrow[t] * KFC + k);
    }
    #pragma unroll
    for (int mt = 0; mt < 2; ++mt) {
      #pragma unroll
      for (int nt = 0; nt < 2; ++nt) {
        acc[mt][nt] = __builtin_amdgcn_mfma_f32_16x16x32_bf16(ah[mt], bh[nt], acc[mt][nt], 0, 0, 0);
        acc[mt][nt] = __builtin_amdgcn_mfma_f32_16x16x32_bf16(ah[mt], bl[nt], acc[mt][nt], 0, 0, 0);
        acc[mt][nt] = __builtin_amdgcn_mfma_f32_16x16x32_bf16(al[mt], bh[nt], acc[mt][nt], 0, 0, 0);
      }
    }
  }

  #pragma unroll
  for (int mt = 0; mt < 2; ++mt) {
    #pragma unroll
    for (int r = 0; r < 4; ++r) {
      const int m = m0 + mt * 16 + lg * 4 + r;
      if (m < cb) {
        #pragma unroll
        for (int nt = 0; nt < 2; ++nt)
          zpart[((size_t)blockIdx.z * cb + m) * NOUT + n0 + nt * 16 + lr] = acc[mt][nt][r];
      }
    }
  }
}

// ---------------------------------------------------------------------------
// K5: fused coord + bilinear gather reading xt (NHWC bf16), XCD-grouped.
// ---------------------------------------------------------------------------
__global__ __launch_bounds__(256) void k_gather(
    const ushort* __restrict__ xt, const float* __restrict__ zpart,
    const float* __restrict__ fcb, float* __restrict__ out, int cb, int b0)
{
  const int bid = blockIdx.x;
  int bl, g;
  if ((cb & 7) == 0) {
    const int xcd = bid & 7;
    const int j   = bid >> 3;
    g  = j & 31;
    bl = (j >> 5) * 8 + xcd;
  } else {
    bl = bid >> 5;
    g  = bid & 31;
  }
  const int node = g * 4 + (threadIdx.x >> 6);
  const int l    = threadIdx.x & 63;
  const int bg   = b0 + bl;

  float val = 0.f;
  if (l < 2 * KS) {
    const int kb = l >> 1, comp = l & 1;
    val = zpart[((size_t)kb * cb + bl) * NOUT + node * 2 + comp];
  }
  #pragma unroll
  for (int off = 2; off < 2 * KS; off <<= 1) val += __shfl_xor(val, off);
  const float z0 = __shfl(val, 0) + fcb[node * 2 + 0];
  const float z1 = __shfl(val, 1) + fcb[node * 2 + 1];
  const float ch = 31.f / (1.f + __expf(-3.f * z0));
  const float cw = 63.f / (1.f + __expf(-3.f * z1));

  if (l < 2)
    out[GF_SIZE + (((size_t)bg * NODES + node) << 1) + l] = l ? cw : ch;

  const float chv = fminf(fmaxf(ch, 0.f), 31.f);
  const float cwv = fminf(fmaxf(cw, 0.f), 63.f);
  const float fh = floorf(chv), fw = floorf(cwv);
  const int h0 = (int)fh, h1i = (int)ceilf(chv);
  const int w0 = (int)fw, w1i = (int)ceilf(cwv);
  const float oh = chv - fh, ow = cwv - fw;
  const ushort* xbp = xt + (size_t)bg * HW * CIN + l;
  const float v_lt = bf2f(xbp[(size_t)(h0 * WW + w0) * CIN]);
  const float v_rt = bf2f(xbp[(size_t)(h1i * WW + w0) * CIN]);
  const float v_lb = bf2f(xbp[(size_t)(h0 * WW + w1i) * CIN]);
  const float v_rb = bf2f(xbp[(size_t)(h1i * WW + w1i) * CIN]);
  const float vt = v_lt + oh * (v_rt - v_lt);
  const float vb = v_lb + oh * (v_rb - v_lb);
  out[((size_t)bg * NODES + node) * CIN + l] = vt + ow * (vb - vt);
}

// ---------------------------------------------------------------------------
extern "C" void kernel_launch(void* const* d_in, const int* in_sizes, int n_in,
                              void* d_out, int out_size, void* d_ws, size_t ws_size,
                              hipStream_t stream)
{
  (void)in_sizes; (void)n_in; (void)out_size;
  const float* x   = (const float*)d_in[0];
  const float* w11 = (const float*)d_in[1];
  const float* b11 = (const float*)d_in[2];
  const float* w12 = (const float*)d_in[3];
  const float* b12 = (const float*)d_in[4];
  const float* w21 = (const float*)d_in[5];
  const float* b21 = (const float*)d_in[6];
  const float* w22 = (const float*)d_in[7];
  const float* b22 = (const float*)d_in[8];
  const float* fcw = (const float*)d_in[9];
  const float* fcb = (const float*)d_in[10];
  float* out = (float*)d_out;
  char* wsb  = (char*)d_ws;

  // fixed: xt 134 MB + h1 67 MB + fcw planes 8 MB. ws_size ~= 1 GiB.
  const size_t xtBytes = (size_t)BATCH * HW * CIN * 2;
  const size_t h1Bytes = (size_t)BATCH * HW * C1 * 2;
  const size_t perB    = 16384 + 16384 + (size_t)KS * NOUT * 4;   // h4 hi/lo + zpart
  const size_t fixed   = xtBytes + h1Bytes + 2 * 4194304;
  size_t avail = ws_size > fixed ? ws_size - fixed : perB;
  size_t cbmax = avail / perB;
  int CB = (int)(cbmax < (size_t)BATCH ? cbmax : (size_t)BATCH);
  if (CB < 1) CB = 1;

  char* p = wsb;
  ushort* xtv  = (ushort*)p;  p += xtBytes;
  ushort* h1v  = (ushort*)p;  p += h1Bytes;
  ushort* h4h  = (ushort*)p;  p += (size_t)CB * 16384;
  ushort* h4l  = (ushort*)p;  p += (size_t)CB * 16384;
  float*  zpv  = (float*)p;   p += (size_t)CB * KS * NOUT * 4;
  ushort* fcwh = (ushort*)p;  p += 4194304;
  ushort* fcwl = (ushort*)p;

  // front: xpose+conv1 (by < BATCH) and cvt_fcw (by >= BATCH) in one launch.
  k_front<<<dim3(8, BATCH + 128), 256, 0, stream>>>(x, w11, b11, fcw, fcwh, fcwl,
                                                    xtv, h1v);

  for (int b0 = 0; b0 < BATCH; b0 += CB) {
    const int cb = (BATCH - b0 < CB) ? (BATCH - b0) : CB;
    k_conv234<<<dim3(4, cb), 256, 0, stream>>>(h1v, w12, b12, w21, b21, w22, b22,
                                               h4h, h4l, b0);
    k_fc<<<dim3((cb + 63) / 64, 4, KS), 256, 0, stream>>>(h4h, h4l, fcwh, fcwl, zpv, cb);
    k_gather<<<dim3(cb * 32), 256, 0, stream>>>(xtv, zpv, fcb, out, cb, b0);
  }
}

// Round 14
// 212.591 us; speedup vs baseline: 1.2937x; 1.0533x over previous
//
#include <hip/hip_runtime.h>
#include <hip/hip_fp16.h>
#include <cstdint>

#define BATCH 512
#define CIN   64
#define HH    32
#define WW    64
#define HW    2048
#define C1    32
#define C2    16
#define C3    8
#define C4    4
#define NOUT  256
#define KFC   8192
#define NODES 128
#define KS    16                      // FC K-split
#define GF_SIZE (BATCH * NODES * CIN)

typedef __attribute__((ext_vector_type(8))) short bfrag;   // 8 bf16 (4 VGPRs)
typedef __attribute__((ext_vector_type(4))) float ffrag;   // 4 fp32 acc

__device__ __forceinline__ ushort bf_trunc(float f) { return (ushort)(__float_as_uint(f) >> 16); }
__device__ __forceinline__ float  bf_truncf(float f) { return __uint_as_float(__float_as_uint(f) & 0xffff0000u); }
__device__ __forceinline__ ushort f2bf(float f) {
  uint32_t u = __float_as_uint(f);
  return (ushort)((u + 0x7fffu + ((u >> 16) & 1u)) >> 16);
}
__device__ __forceinline__ uint32_t pack2(float a, float b) {
  return (uint32_t)f2bf(a) | ((uint32_t)f2bf(b) << 16);
}
__device__ __forceinline__ uint32_t packhi2(float a, float b) {
  return (uint32_t)bf_trunc(a) | ((uint32_t)bf_trunc(b) << 16);
}
__device__ __forceinline__ ushort f2h(float f) { return __half_as_ushort(__float2half_rn(f)); }
__device__ __forceinline__ uint32_t packh2(float a, float b) {
  return (uint32_t)f2h(a) | ((uint32_t)f2h(b) << 16);
}
__device__ __forceinline__ float h2f(uint32_t u) { return __half2float(__ushort_as_half((ushort)u)); }
__device__ __forceinline__ float bf2f(ushort u) { return __uint_as_float(((uint32_t)u) << 16); }

__device__ __forceinline__ bfrag ld_frag4(const uint32_t* tp) {
  union { uint32_t u[4]; bfrag b; } c;
  c.u[0] = tp[0]; c.u[1] = tp[1]; c.u[2] = tp[2]; c.u[3] = tp[3];
  return c.b;
}

// ---------------------------------------------------------------------------
// K0 "front": xpose + conv1 + cvt_fcw, one launch (R13-proven).
// ---------------------------------------------------------------------------
__global__ __launch_bounds__(256) void k_front(
    const float* __restrict__ x, const float* __restrict__ w11, const float* __restrict__ b11,
    const float* __restrict__ fcw, ushort* __restrict__ fcwh, ushort* __restrict__ fcwl,
    ushort* __restrict__ xt, ushort* __restrict__ h1g)
{
  if (blockIdx.y >= BATCH) {   // ---- cvt_fcw branch
    const int chunk = (blockIdx.y - BATCH) * 8 + blockIdx.x;
    const int i = (chunk * 256 + threadIdx.x) * 8;
    const float4 a = *(const float4*)(fcw + i);
    const float4 b = *(const float4*)(fcw + i + 4);
    uint4 hv, lv;
    hv.x = packhi2(a.x, a.y); hv.y = packhi2(a.z, a.w);
    hv.z = packhi2(b.x, b.y); hv.w = packhi2(b.z, b.w);
    lv.x = pack2(a.x - bf_truncf(a.x), a.y - bf_truncf(a.y));
    lv.y = pack2(a.z - bf_truncf(a.z), a.w - bf_truncf(a.w));
    lv.z = pack2(b.x - bf_truncf(b.x), b.y - bf_truncf(b.y));
    lv.w = pack2(b.z - bf_truncf(b.z), b.w - bf_truncf(b.w));
    *(uint4*)(fcwh + i) = hv;
    *(uint4*)(fcwl + i) = lv;
    return;
  }

  __shared__ uint32_t tb[256 * 33];
  const int t  = threadIdx.x;
  const int b  = blockIdx.y;
  const int rg = blockIdx.x;                 // 4-row group, 256 px
  {
    const float* xp = x + (size_t)b * CIN * HW + rg * 256 + t;
    #pragma unroll
    for (int j = 0; j < 32; ++j) {
      float v0 = xp[(size_t)(2 * j) * HW];
      float v1 = xp[(size_t)(2 * j + 1) * HW];
      tb[t * 33 + j] = pack2(v0, v1);
    }
  }
  __syncthreads();

  // xt stores: consecutive uint4 per consecutive lane = 4 KB/wave-inst.
  {
    ushort* op = xt + ((size_t)b * HW + rg * 256) * CIN;
    #pragma unroll
    for (int k = 0; k < 8; ++k) {
      const int u = k * 256 + t;
      const int p = u >> 3, q = u & 7;
      uint4 v;
      v.x = tb[p * 33 + q * 4 + 0];
      v.y = tb[p * 33 + q * 4 + 1];
      v.z = tb[p * 33 + q * 4 + 2];
      v.w = tb[p * 33 + q * 4 + 3];
      *(uint4*)(op + (size_t)u * 8) = v;
    }
  }

  // conv1 (1x1, 64->32) via MFMA from staged LDS. 16 px-tiles, 4/wave.
  const int l  = t & 63;
  const int wv = t >> 6;
  const int lr = l & 15;
  const int lg = l >> 4;
  bfrag w1h[2][2], w1l[2][2];
  #pragma unroll
  for (int m = 0; m < 2; ++m) {
    #pragma unroll
    for (int ks = 0; ks < 2; ++ks) {
      const float* wp = w11 + (m * 16 + lr) * 64 + ks * 32 + lg * 8;
      #pragma unroll
      for (int e = 0; e < 8; ++e) {
        float v = wp[e];
        w1h[m][ks][e] = (short)bf_trunc(v);
        w1l[m][ks][e] = (short)f2bf(v - bf_truncf(v));
      }
    }
  }
  float bias1[2][4];
  #pragma unroll
  for (int m = 0; m < 2; ++m) {
    #pragma unroll
    for (int r = 0; r < 4; ++r) bias1[m][r] = b11[m * 16 + lg * 4 + r];
  }

  #pragma unroll
  for (int i = 0; i < 4; ++i) {
    const int pxl = (wv * 4 + i) * 16 + lr;            // 0..255
    const bfrag f0 = ld_frag4(&tb[pxl * 33 + lg * 4]);
    const bfrag f1 = ld_frag4(&tb[pxl * 33 + 16 + lg * 4]);
    ffrag a0 = {0.f, 0.f, 0.f, 0.f}, a1 = {0.f, 0.f, 0.f, 0.f};
    a0 = __builtin_amdgcn_mfma_f32_16x16x32_bf16(w1h[0][0], f0, a0, 0, 0, 0);
    a0 = __builtin_amdgcn_mfma_f32_16x16x32_bf16(w1l[0][0], f0, a0, 0, 0, 0);
    a0 = __builtin_amdgcn_mfma_f32_16x16x32_bf16(w1h[0][1], f1, a0, 0, 0, 0);
    a0 = __builtin_amdgcn_mfma_f32_16x16x32_bf16(w1l[0][1], f1, a0, 0, 0, 0);
    a1 = __builtin_amdgcn_mfma_f32_16x16x32_bf16(w1h[1][0], f0, a1, 0, 0, 0);
    a1 = __builtin_amdgcn_mfma_f32_16x16x32_bf16(w1l[1][0], f0, a1, 0, 0, 0);
    a1 = __builtin_amdgcn_mfma_f32_16x16x32_bf16(w1h[1][1], f1, a1, 0, 0, 0);
    a1 = __builtin_amdgcn_mfma_f32_16x16x32_bf16(w1l[1][1], f1, a1, 0, 0, 0);
    ushort* hp = h1g + ((size_t)b * HW + rg * 256 + pxl) * C1;
    #pragma unroll
    for (int m = 0; m < 2; ++m) {
      float v0 = fmaxf((m ? a1[0] : a0[0]) + bias1[m][0], 0.f);
      float v1 = fmaxf((m ? a1[1] : a0[1]) + bias1[m][1], 0.f);
      float v2 = fmaxf((m ? a1[2] : a0[2]) + bias1[m][2], 0.f);
      float v3 = fmaxf((m ? a1[3] : a0[3]) + bias1[m][3], 0.f);
      *(uint2*)(hp + m * 16 + lg * 4) = uint2{pack2(v0, v1), pack2(v2, v3)};
    }
  }
}

// ---------------------------------------------------------------------------
// K1: conv2+conv3+conv4 fused (R13 structure). Round-14: h4 written as a
// SINGLE RTN-bf16 plane (fc error budget allows it; see analysis), and the
// redundant pad-sync removed (pad writes and bulk loads are LDS-disjoint).
// ---------------------------------------------------------------------------
__global__ __launch_bounds__(256) void k_conv234(
    const ushort* __restrict__ h1g, const float* __restrict__ w12, const float* __restrict__ b12,
    const float* __restrict__ w21, const float* __restrict__ b21,
    const float* __restrict__ w22, const float* __restrict__ b22,
    ushort* __restrict__ h4, int b0)
{
  __shared__ __align__(16) char smem[12 * 66 * 64];   // 50688 B
  const int tid = threadIdx.x;
  const int l   = tid & 63;
  const int wv  = tid >> 6;    // 0..3
  const int lr  = l & 15;
  const int lg  = l >> 4;
  const int r0  = blockIdx.x * 8;
  const int bg  = b0 + blockIdx.y;

  // zero padded cols (colb 0 and 65) of all 12 rows (disjoint from bulk loads)
  if (tid < 192) {
    int row = tid >> 4, half = (tid >> 3) & 1, q = tid & 7;
    int cell = row * 66 + (half ? 65 : 0);
    *(uint2*)(smem + (cell << 6) + q * 8) = uint2{0u, 0u};
  }

  // h1 rows r0-2..r0+9 -> LDS (swizzled). One row per 256-thread pass.
  {
    const int px = tid >> 2, q = tid & 3;        // q = logical 8-ch group
    const int colb  = px + 1;
    const int chunk = q ^ ((colb >> 1) & 3);
    #pragma unroll
    for (int ry = 0; ry < 12; ++ry) {
      const int y = r0 - 2 + ry;
      uint4 v = uint4{0u, 0u, 0u, 0u};
      if (y >= 0 && y < HH)
        v = *(const uint4*)(h1g + ((size_t)bg * HW + y * WW + px) * C1 + q * 8);
      *(uint4*)(smem + ((ry * 66 + colb) << 6) + (chunk << 4)) = v;
    }
  }
  __syncthreads();

  // W2 fragments from global.
  bfrag w2h[9], w2l[9];
  #pragma unroll
  for (int t = 0; t < 9; ++t) {
    const float* wp = w12 + lr * 288 + t;
    #pragma unroll
    for (int e = 0; e < 8; ++e) {
      float v = wp[(lg * 8 + e) * 9];
      w2h[t][e] = (short)bf_trunc(v);
      w2l[t][e] = (short)f2bf(v - bf_truncf(v));
    }
  }
  float bias2[4];
  #pragma unroll
  for (int r = 0; r < 4; ++r) bias2[r] = b12[lg * 4 + r];

  // Phase B: conv2 -> h2 fp16 in regs. 40 tiles (10 rows x 4), 10/wave.
  uint32_t ph0[10], ph1[10];
  #pragma unroll
  for (int i = 0; i < 10; ++i) {
    const int nt   = wv * 10 + i;
    const int hryo = nt >> 2;             // 0..9
    const int col0 = (nt & 3) << 4;
    ffrag acc = {0.f, 0.f, 0.f, 0.f};
    #pragma unroll
    for (int ky = 0; ky < 3; ++ky) {
      const int row = hryo + ky;
      #pragma unroll
      for (int kx = 0; kx < 3; ++kx) {
        const int colb  = col0 + lr + kx;
        const int chunk = lg ^ ((colb >> 1) & 3);
        const bfrag hv = *(const bfrag*)(smem + ((row * 66 + colb) << 6) + (chunk << 4));
        acc = __builtin_amdgcn_mfma_f32_16x16x32_bf16(w2h[ky * 3 + kx], hv, acc, 0, 0, 0);
        acc = __builtin_amdgcn_mfma_f32_16x16x32_bf16(w2l[ky * 3 + kx], hv, acc, 0, 0, 0);
      }
    }
    ph0[i] = packh2(fmaxf(acc[0] + bias2[0], 0.f), fmaxf(acc[1] + bias2[1], 0.f));
    ph1[i] = packh2(fmaxf(acc[2] + bias2[2], 0.f), fmaxf(acc[3] + bias2[3], 0.f));
  }
  __syncthreads();   // all h1 reads done; smem reusable

  // h2 regs -> LDS: [10 rows][64 px][16 ch fp16] = 20480 B at smem base.
  #pragma unroll
  for (int i = 0; i < 10; ++i) {
    const int nt   = wv * 10 + i;
    const int hryo = nt >> 2;
    const int col  = ((nt & 3) << 4) + lr;
    *(uint2*)(smem + ((hryo * 64 + col) << 5) + lg * 8) = uint2{ph0[i], ph1[i]};
  }
  __syncthreads();

  // Phase C1: conv3 (1x1, 16->8) -> h3 fp32 LDS [10][64][9] @ +20480.
  float* h3b = (float*)(smem + 20480);
  for (int p = tid; p < 640; p += 256) {
    const int ry = p >> 6, wc = p & 63;
    const int y  = r0 - 1 + ry;
    float* hd = h3b + (ry * 64 + wc) * 9;
    if (y >= 0 && y < HH) {
      const uint4 ua = *(const uint4*)(smem + ((ry * 64 + wc) << 5));
      const uint4 ub = *(const uint4*)(smem + ((ry * 64 + wc) << 5) + 16);
      uint32_t uw[8] = {ua.x, ua.y, ua.z, ua.w, ub.x, ub.y, ub.z, ub.w};
      float xv[16];
      #pragma unroll
      for (int j = 0; j < 8; ++j) {
        xv[2*j]   = h2f(uw[j] & 0xffffu);
        xv[2*j+1] = h2f(uw[j] >> 16);
      }
      float acc[C3];
      #pragma unroll
      for (int o = 0; o < C3; ++o) acc[o] = b21[o];
      #pragma unroll
      for (int c = 0; c < 16; ++c) {
        float v = xv[c];
        #pragma unroll
        for (int o = 0; o < C3; ++o)
          acc[o] = fmaf(v, w21[o * 16 + c], acc[o]);   // uniform -> s_load
      }
      #pragma unroll
      for (int c = 0; c < C3; ++c) hd[c] = fmaxf(acc[c], 0.f);
    } else {
      #pragma unroll
      for (int c = 0; c < C3; ++c) hd[c] = 0.f;
    }
  }
  __syncthreads();

  // Phase C2: conv4 (3x3, 8->4) -> h4 single bf16 (RTN) global.
  for (int p = tid; p < 512; p += 256) {
    const int yl = p >> 6, wc = p & 63, ry = yl + 1;
    float acc[C4] = {b22[0], b22[1], b22[2], b22[3]};
    #pragma unroll
    for (int ky = 0; ky < 3; ++ky) {
      #pragma unroll
      for (int kx = 0; kx < 3; ++kx) {
        const int wcc = wc + kx - 1;
        if (wcc < 0 || wcc >= WW) continue;
        const float* hb = h3b + ((ry + ky - 1) * 64 + wcc) * 9;
        const int tap = ky * 3 + kx;
        #pragma unroll
        for (int c = 0; c < C3; ++c) {
          float v = hb[c];
          #pragma unroll
          for (int o = 0; o < C4; ++o)
            acc[o] = fmaf(v, w22[(o * 8 + c) * 9 + tap], acc[o]);  // s_load
        }
      }
    }
    const size_t base = (size_t)blockIdx.y * KFC + (r0 + yl) * WW + wc;
    #pragma unroll
    for (int o = 0; o < C4; ++o)
      h4[base + (size_t)o * HW] = f2bf(fmaxf(acc[o], 0.f));
  }
}

// ---------------------------------------------------------------------------
// K3: FC GEMM. Round-14: A = h4 single bf16; B = fcw hi/lo -> 2 MFMAs.
// ---------------------------------------------------------------------------
__global__ __launch_bounds__(256) void k_fc(
    const ushort* __restrict__ Ap_, const ushort* __restrict__ Bhp,
    const ushort* __restrict__ Blp, float* __restrict__ zpart, int cb)
{
  const int tid = threadIdx.x;
  const int l   = tid & 63;
  const int wv  = tid >> 6;
  const int lr  = l & 15;
  const int lg  = l >> 4;
  const int m0  = blockIdx.x * 64 + (wv >> 1) * 32;
  const int n0  = blockIdx.y * 64 + (wv & 1) * 32;
  const int k0  = blockIdx.z * (KFC / KS);     // 512 per split

  int mrow[2], nrow[2];
  #pragma unroll
  for (int t = 0; t < 2; ++t) {
    int m = m0 + t * 16 + lr;
    mrow[t] = m < cb ? m : cb - 1;             // clamp; masked at write
    nrow[t] = n0 + t * 16 + lr;
  }
  ffrag acc[2][2] = {};

  #pragma unroll 1
  for (int kc = 0; kc < (KFC / KS) / 32; ++kc) {
    const int k = k0 + kc * 32 + lg * 8;
    bfrag ah[2], bh[2], bl[2];
    #pragma unroll
    for (int t = 0; t < 2; ++t) {
      ah[t] = *(const bfrag*)(Ap_ + (size_t)mrow[t] * KFC + k);
      bh[t] = *(const bfrag*)(Bhp + (size_t)nrow[t] * KFC + k);
      bl[t] = *(const bfrag*)(Blp + (size_t)nrow[t] * KFC + k);
    }
    #pragma unroll
    for (int mt = 0; mt < 2; ++mt) {
      #pragma unroll
      for (int nt = 0; nt < 2; ++nt) {
        acc[mt][nt] = __builtin_amdgcn_mfma_f32_16x16x32_bf16(ah[mt], bh[nt], acc[mt][nt], 0, 0, 0);
        acc[mt][nt] = __builtin_amdgcn_mfma_f32_16x16x32_bf16(ah[mt], bl[nt], acc[mt][nt], 0, 0, 0);
      }
    }
  }

  #pragma unroll
  for (int mt = 0; mt < 2; ++mt) {
    #pragma unroll
    for (int r = 0; r < 4; ++r) {
      const int m = m0 + mt * 16 + lg * 4 + r;
      if (m < cb) {
        #pragma unroll
        for (int nt = 0; nt < 2; ++nt)
          zpart[((size_t)blockIdx.z * cb + m) * NOUT + n0 + nt * 16 + lr] = acc[mt][nt][r];
      }
    }
  }
}

// ---------------------------------------------------------------------------
// K5: fused coord + bilinear gather reading xt (NHWC bf16), XCD-grouped.
// ---------------------------------------------------------------------------
__global__ __launch_bounds__(256) void k_gather(
    const ushort* __restrict__ xt, const float* __restrict__ zpart,
    const float* __restrict__ fcb, float* __restrict__ out, int cb, int b0)
{
  const int bid = blockIdx.x;
  int bl, g;
  if ((cb & 7) == 0) {
    const int xcd = bid & 7;
    const int j   = bid >> 3;
    g  = j & 31;
    bl = (j >> 5) * 8 + xcd;
  } else {
    bl = bid >> 5;
    g  = bid & 31;
  }
  const int node = g * 4 + (threadIdx.x >> 6);
  const int l    = threadIdx.x & 63;
  const int bg   = b0 + bl;

  float val = 0.f;
  if (l < 2 * KS) {
    const int kb = l >> 1, comp = l & 1;
    val = zpart[((size_t)kb * cb + bl) * NOUT + node * 2 + comp];
  }
  #pragma unroll
  for (int off = 2; off < 2 * KS; off <<= 1) val += __shfl_xor(val, off);
  const float z0 = __shfl(val, 0) + fcb[node * 2 + 0];
  const float z1 = __shfl(val, 1) + fcb[node * 2 + 1];
  const float ch = 31.f / (1.f + __expf(-3.f * z0));
  const float cw = 63.f / (1.f + __expf(-3.f * z1));

  if (l < 2)
    out[GF_SIZE + (((size_t)bg * NODES + node) << 1) + l] = l ? cw : ch;

  const float chv = fminf(fmaxf(ch, 0.f), 31.f);
  const float cwv = fminf(fmaxf(cw, 0.f), 63.f);
  const float fh = floorf(chv), fw = floorf(cwv);
  const int h0 = (int)fh, h1i = (int)ceilf(chv);
  const int w0 = (int)fw, w1i = (int)ceilf(cwv);
  const float oh = chv - fh, ow = cwv - fw;
  const ushort* xbp = xt + (size_t)bg * HW * CIN + l;
  const float v_lt = bf2f(xbp[(size_t)(h0 * WW + w0) * CIN]);
  const float v_rt = bf2f(xbp[(size_t)(h1i * WW + w0) * CIN]);
  const float v_lb = bf2f(xbp[(size_t)(h0 * WW + w1i) * CIN]);
  const float v_rb = bf2f(xbp[(size_t)(h1i * WW + w1i) * CIN]);
  const float vt = v_lt + oh * (v_rt - v_lt);
  const float vb = v_lb + oh * (v_rb - v_lb);
  out[((size_t)bg * NODES + node) * CIN + l] = vt + ow * (vb - vt);
}

// ---------------------------------------------------------------------------
extern "C" void kernel_launch(void* const* d_in, const int* in_sizes, int n_in,
                              void* d_out, int out_size, void* d_ws, size_t ws_size,
                              hipStream_t stream)
{
  (void)in_sizes; (void)n_in; (void)out_size;
  const float* x   = (const float*)d_in[0];
  const float* w11 = (const float*)d_in[1];
  const float* b11 = (const float*)d_in[2];
  const float* w12 = (const float*)d_in[3];
  const float* b12 = (const float*)d_in[4];
  const float* w21 = (const float*)d_in[5];
  const float* b21 = (const float*)d_in[6];
  const float* w22 = (const float*)d_in[7];
  const float* b22 = (const float*)d_in[8];
  const float* fcw = (const float*)d_in[9];
  const float* fcb = (const float*)d_in[10];
  float* out = (float*)d_out;
  char* wsb  = (char*)d_ws;

  // fixed: xt 134 MB + h1 67 MB + fcw planes 16 MB. ws_size ~= 1 GiB.
  const size_t xtBytes = (size_t)BATCH * HW * CIN * 2;
  const size_t h1Bytes = (size_t)BATCH * HW * C1 * 2;
  const size_t perB    = 16384 + (size_t)KS * NOUT * 4;   // h4 single + zpart
  const size_t fixed   = xtBytes + h1Bytes + 2 * 4194304;
  size_t avail = ws_size > fixed ? ws_size - fixed : perB;
  size_t cbmax = avail / perB;
  int CB = (int)(cbmax < (size_t)BATCH ? cbmax : (size_t)BATCH);
  if (CB < 1) CB = 1;

  char* p = wsb;
  ushort* xtv  = (ushort*)p;  p += xtBytes;
  ushort* h1v  = (ushort*)p;  p += h1Bytes;
  ushort* h4v  = (ushort*)p;  p += (size_t)CB * 16384;
  float*  zpv  = (float*)p;   p += (size_t)CB * KS * NOUT * 4;
  ushort* fcwh = (ushort*)p;  p += 4194304;
  ushort* fcwl = (ushort*)p;

  k_front<<<dim3(8, BATCH + 128), 256, 0, stream>>>(x, w11, b11, fcw, fcwh, fcwl,
                                                    xtv, h1v);

  for (int b0 = 0; b0 < BATCH; b0 += CB) {
    const int cb = (BATCH - b0 < CB) ? (BATCH - b0) : CB;
    k_conv234<<<dim3(4, cb), 256, 0, stream>>>(h1v, w12, b12, w21, b21, w22, b22,
                                               h4v, b0);
    k_fc<<<dim3((cb + 63) / 64, 4, KS), 256, 0, stream>>>(h4v, fcwh, fcwl, zpv, cb);
    k_gather<<<dim3(cb * 32), 256, 0, stream>>>(xtv, zpv, fcb, out, cb, b0);
  }
}